// Round 12
// baseline (5450.485 us; speedup 1.0000x reference)
//
#include <hip/hip_runtime.h>

#define TLEN 1024
#define HID  96
#define NTHR 768
#define WPAD 49   // LDS weight row stride (floats): 12 float4 + 1 pad; 17l mod 32 bank-spread

__device__ __forceinline__ float sigf(float x) { return 1.0f / (1.0f + __expf(-x)); }
__device__ __forceinline__ float tanh_fast(float x) {
    float e = __expf(2.0f * x);
    return 1.0f - 2.0f / (e + 1.0f);
}

// VALU-pipe lane combine: s += s(from lane per dpp_ctrl). No LDS pipe use.
template <int CTRL>
__device__ __forceinline__ float dpp_add(float s) {
    int t = __builtin_amdgcn_update_dpp(0, __float_as_int(s), CTRL, 0xF, 0xF, true);
    return s + __int_as_float(t);
}
#define DPP_XOR1   0xB1   // quad_perm [1,0,3,2]: lane i <- lane i^1
#define DPP_XOR2   0x4E   // quad_perm [2,3,0,1]: lane i <- lane i^2
#define DPP_HMIRR  0x141  // row_half_mirror: lane i <- (i&~7)+(7-(i&7))
#define DPP_ROR8   0x128  // row_ror:8 (symmetric mod 16)

#define RED8(S)  S = dpp_add<DPP_XOR1>(S); S = dpp_add<DPP_XOR2>(S); S = dpp_add<DPP_HMIRR>(S);

#define DOT4(A, W, H)                         \
    (A).x = fmaf((W).x, (H).x, (A).x);        \
    (A).y = fmaf((W).y, (H).y, (A).y);        \
    (A).z = fmaf((W).z, (H).z, (A).z);        \
    (A).w = fmaf((W).w, (H).w, (A).w);

extern "C" __global__ void __launch_bounds__(NTHR)
__attribute__((amdgpu_waves_per_eu(3, 3)))
lstm2_fused(const float* __restrict__ x,
            const float* __restrict__ Wih0, const float* __restrict__ Whh0,
            const float* __restrict__ bih0, const float* __restrict__ bhh0,
            const float* __restrict__ Wih1, const float* __restrict__ Whh1,
            const float* __restrict__ bih1, const float* __restrict__ bhh1,
            const float* __restrict__ Wl,   const float* __restrict__ bl,
            float* __restrict__ out)
{
    __shared__ __attribute__((aligned(16))) float x_s[TLEN];
    __shared__ __attribute__((aligned(16))) float out_s[TLEN];
    __shared__ __attribute__((aligned(16))) float h1b[2 * HID];  // double-buffered
    __shared__ __attribute__((aligned(16))) float h2b[2 * HID];
    // Layer-2 gate-g AND gate-o weights in LDS (12 float4/thread). Register
    // weights drop to 96 floats -> invariants (~109) fit the 84-AGPR park +
    // 25 arch slots, ending the per-step scratch rotation (R10: 3.1GB, R11:
    // 1.9GB of spill write-backs). Total LDS 160,256B -> 1 block/CU.
    __shared__ __attribute__((aligned(16))) float wlds[NTHR * WPAD];  // 147 KB

    const int tid = threadIdx.x;
    const int b   = blockIdx.x;
    const int u   = tid >> 3;   // unit 0..95
    const int kq  = tid & 7;    // K-slice index 0..7

    for (int i = tid; i < TLEN; i += NTHR) {
        x_s[i]   = x[b * TLEN + i];
        out_s[i] = 0.0f;
    }
    if (tid < 2 * HID) { h1b[tid] = 0.0f; h2b[tid] = 0.0f; }

    // ---- Layer-1 weights (regs): gate g row = 96g+u, f4-cols [3kq, 3kq+3) ----
    const float4* W0 = reinterpret_cast<const float4*>(Whh0);
    const float4* p;
    p = W0 + (      u) * 24 + 3 * kq;  float4 a00 = p[0], a01 = p[1], a02 = p[2];
    p = W0 + ( 96 + u) * 24 + 3 * kq;  float4 a10 = p[0], a11 = p[1], a12 = p[2];
    p = W0 + (192 + u) * 24 + 3 * kq;  float4 a20 = p[0], a21 = p[1], a22 = p[2];
    p = W0 + (288 + u) * 24 + 3 * kq;  float4 a30 = p[0], a31 = p[1], a32 = p[2];

    // ---- Layer-2 weights: K=192=[Wih1|Whh1]; kq<4 -> Wih1 cols 24kq.., else Whh1.
    //      Gates i,f (12 f4) in regs; gates g,o (12 f4) -> LDS.
    const float4* W1 = reinterpret_cast<const float4*>(kq < 4 ? Wih1 : Whh1);
    const int c6 = 6 * (kq & 3);
    p = W1 + (      u) * 24 + c6;  float4 b00=p[0],b01=p[1],b02=p[2],b03=p[3],b04=p[4],b05=p[5];
    p = W1 + ( 96 + u) * 24 + c6;  float4 b10=p[0],b11=p[1],b12=p[2],b13=p[3],b14=p[4],b15=p[5];
    {
        float4* wl = reinterpret_cast<float4*>(wlds + tid * WPAD);
        p = W1 + (288 + u) * 24 + c6;   // gate o -> wl[0..5]
        wl[0] = p[0]; wl[1] = p[1]; wl[2] = p[2];
        wl[3] = p[3]; wl[4] = p[4]; wl[5] = p[5];
        p = W1 + (192 + u) * 24 + c6;   // gate g -> wl[6..11]
        wl[6] = p[0]; wl[7] = p[1]; wl[8] = p[2];
        wl[9] = p[3]; wl[10] = p[4]; wl[11] = p[5];
    }

    // ---- per-lane bias/x-term carriers (enter gate g via lane kq==g pre-reduce) ----
    float biasA = 0.0f, wxA = 0.0f, biasC = 0.0f;
    if (kq < 4) { int r = 96 * kq + u;       biasA = bih0[r] + bhh0[r]; wxA = Wih0[r]; }
    else        { int r = 96 * (kq - 4) + u; biasC = bih1[r] + bhh1[r]; }
    const float m0  = (kq == 0) ? 1.0f : 0.0f;
    const float m1  = (kq == 1) ? 1.0f : 0.0f;
    const float m2  = (kq == 2) ? 1.0f : 0.0f;
    const float m3  = (kq == 3) ? 1.0f : 0.0f;
    const float mc0 = (kq == 4) ? 1.0f : 0.0f;
    const float mc1 = (kq == 5) ? 1.0f : 0.0f;
    const float mc2 = (kq == 6) ? 1.0f : 0.0f;
    const float mc3 = (kq == 7) ? 1.0f : 0.0f;
    const float wl_u = (kq == 0) ? Wl[u] : 0.0f;
    const float bl0  = bl[0];

    float c1 = 0.0f, c2 = 0.0f;   // cell state, valid in lane kq==0 only
    __syncthreads();

    #pragma unroll 1
    for (int t = 0; t < TLEN; ++t) {
        const int rd = t & 1, wb = rd ^ 1;
        const float xt = x_s[t];

        // ---- Layer 1: 4 gate partial-dots over cols [12kq,12kq+12) ----
        {
            const float4* hA = reinterpret_cast<const float4*>(h1b + rd * HID) + 3 * kq;
            float4 q0 = {0,0,0,0}, q1 = {0,0,0,0}, q2 = {0,0,0,0}, q3 = {0,0,0,0};
            float4 h4;
            h4 = hA[0]; DOT4(q0,a00,h4) DOT4(q1,a10,h4) DOT4(q2,a20,h4) DOT4(q3,a30,h4)
            h4 = hA[1]; DOT4(q0,a01,h4) DOT4(q1,a11,h4) DOT4(q2,a21,h4) DOT4(q3,a31,h4)
            h4 = hA[2]; DOT4(q0,a02,h4) DOT4(q1,a12,h4) DOT4(q2,a22,h4) DOT4(q3,a32,h4)
            float s0 = (q0.x + q0.y) + (q0.z + q0.w);
            float s1 = (q1.x + q1.y) + (q1.z + q1.w);
            float s2 = (q2.x + q2.y) + (q2.z + q2.w);
            float s3 = (q3.x + q3.y) + (q3.z + q3.w);
            const float bwx = fmaf(wxA, xt, biasA);
            s0 = fmaf(m0, bwx, s0); s1 = fmaf(m1, bwx, s1);
            s2 = fmaf(m2, bwx, s2); s3 = fmaf(m3, bwx, s3);
            RED8(s0) RED8(s1) RED8(s2) RED8(s3)
            if (kq == 0) {
                float gi = sigf(s0), gf = sigf(s1), gc = tanh_fast(s2), go = sigf(s3);
                c1 = gf * c1 + gi * gc;
                h1b[wb * HID + u] = go * tanh_fast(c1);
            }
        }
        __syncthreads();   // the ONLY barrier per step
        // ---- Layer 2: cols [24kq..): kq<4 over h1_t (new), kq>=4 over h2_{t-1} ----
        {
            const float4* hC = (kq < 4)
                ? reinterpret_cast<const float4*>(h1b + wb * HID) + 6 * kq
                : reinterpret_cast<const float4*>(h2b + rd * HID) + 6 * (kq - 4);
            // gates g,o weights stream from LDS; opaque zr keeps the 12
            // loop-invariant float4s from being LICM-hoisted back into regs
            int zr;
            asm volatile("v_mov_b32 %0, 0" : "=v"(zr));
            const float4* wl = reinterpret_cast<const float4*>(wlds + tid * WPAD + zr);
            float4 q0 = {0,0,0,0}, q1 = {0,0,0,0}, q2 = {0,0,0,0}, q3 = {0,0,0,0};
            float4 h4;
            h4 = hC[0]; DOT4(q0,b00,h4) DOT4(q1,b10,h4) DOT4(q2,wl[6],h4)  DOT4(q3,wl[0],h4)
            h4 = hC[1]; DOT4(q0,b01,h4) DOT4(q1,b11,h4) DOT4(q2,wl[7],h4)  DOT4(q3,wl[1],h4)
            h4 = hC[2]; DOT4(q0,b02,h4) DOT4(q1,b12,h4) DOT4(q2,wl[8],h4)  DOT4(q3,wl[2],h4)
            h4 = hC[3]; DOT4(q0,b03,h4) DOT4(q1,b13,h4) DOT4(q2,wl[9],h4)  DOT4(q3,wl[3],h4)
            h4 = hC[4]; DOT4(q0,b04,h4) DOT4(q1,b14,h4) DOT4(q2,wl[10],h4) DOT4(q3,wl[4],h4)
            h4 = hC[5]; DOT4(q0,b05,h4) DOT4(q1,b15,h4) DOT4(q2,wl[11],h4) DOT4(q3,wl[5],h4)
            float s0 = (q0.x + q0.y) + (q0.z + q0.w);
            float s1 = (q1.x + q1.y) + (q1.z + q1.w);
            float s2 = (q2.x + q2.y) + (q2.z + q2.w);
            float s3 = (q3.x + q3.y) + (q3.z + q3.w);
            s0 = fmaf(mc0, biasC, s0); s1 = fmaf(mc1, biasC, s1);
            s2 = fmaf(mc2, biasC, s2); s3 = fmaf(mc3, biasC, s3);
            RED8(s0) RED8(s1) RED8(s2) RED8(s3)
            float po = 0.0f;
            if (kq == 0) {
                float gi = sigf(s0), gf = sigf(s1), gc = tanh_fast(s2), go = sigf(s3);
                c2 = gf * c2 + gi * gc;
                float h2v = go * tanh_fast(c2);
                h2b[wb * HID + u] = h2v;
                po = wl_u * h2v;
            }
            // wave-sum of the 8 unit-leaders, then one atomic per wave
            po = dpp_add<DPP_ROR8>(po);
            po += __shfl_xor(po, 16);
            po += __shfl_xor(po, 32);
            if ((tid & 63) == 0) atomicAdd(&out_s[t], po + ((tid == 0) ? bl0 : 0.0f));
        }
        // no trailing barrier needed: next step's L1 writes h1b[rd], which no
        // thread reads after this step's barrier (L2 reads h1b[wb]/h2b[rd]),
        // and all threads left L1(t) before the barrier released anyone.
    }
    __syncthreads();
    for (int i = tid; i < TLEN; i += NTHR) out[b * TLEN + i] = out_s[i];
}

extern "C" void kernel_launch(void* const* d_in, const int* in_sizes, int n_in,
                              void* d_out, int out_size, void* d_ws, size_t ws_size,
                              hipStream_t stream)
{
    (void)in_sizes; (void)n_in; (void)d_ws; (void)ws_size; (void)out_size;
    const float* x    = (const float*)d_in[0];
    const float* Wih0 = (const float*)d_in[1];
    const float* Whh0 = (const float*)d_in[2];
    const float* bih0 = (const float*)d_in[3];
    const float* bhh0 = (const float*)d_in[4];
    const float* Wih1 = (const float*)d_in[5];
    const float* Whh1 = (const float*)d_in[6];
    const float* bih1 = (const float*)d_in[7];
    const float* bhh1 = (const float*)d_in[8];
    const float* Wl   = (const float*)d_in[9];
    const float* bl   = (const float*)d_in[10];

    lstm2_fused<<<dim3(256), dim3(NTHR), 0, stream>>>(
        x, Wih0, Whh0, bih0, bhh0, Wih1, Whh1, bih1, bhh1, Wl, bl,
        (float*)d_out);
}

// Round 13
// 2596.918 us; speedup vs baseline: 2.0988x; 2.0988x over previous
//
#include <hip/hip_runtime.h>

#define TLEN 1024
#define HID  96
#define NTHR 768

__device__ __forceinline__ float sigf(float x) { return 1.0f / (1.0f + __expf(-x)); }
__device__ __forceinline__ float tanh_fast(float x) {
    float e = __expf(2.0f * x);
    return 1.0f - 2.0f / (e + 1.0f);
}

template <int CTRL>
__device__ __forceinline__ float dpp_add(float s) {
    int t = __builtin_amdgcn_update_dpp(0, __float_as_int(s), CTRL, 0xF, 0xF, true);
    return s + __int_as_float(t);
}
#define DPP_XOR1   0xB1   // quad_perm [1,0,3,2]
#define DPP_XOR2   0x4E   // quad_perm [2,3,0,1]
#define DPP_HMIRR  0x141  // row_half_mirror (direction-proof; R10-verified)

#define RED8(S)  S = dpp_add<DPP_XOR1>(S); S = dpp_add<DPP_XOR2>(S); S = dpp_add<DPP_HMIRR>(S);

#define DOT4(A, W, H)                         \
    (A).x = fmaf((W).x, (H).x, (A).x);        \
    (A).y = fmaf((W).y, (H).y, (A).y);        \
    (A).z = fmaf((W).z, (H).z, (A).z);        \
    (A).w = fmaf((W).w, (H).w, (A).w);

extern "C" __global__ void __launch_bounds__(NTHR)
__attribute__((amdgpu_waves_per_eu(3, 3)))
lstm2_fused(const float* __restrict__ x,
            const float* __restrict__ Wih0, const float* __restrict__ Whh0,
            const float* __restrict__ bih0, const float* __restrict__ bhh0,
            const float* __restrict__ Wih1, const float* __restrict__ Whh1,
            const float* __restrict__ bih1, const float* __restrict__ bhh1,
            const float* __restrict__ Wl,   const float* __restrict__ bl,
            float* __restrict__ out)
{
    __shared__ __attribute__((aligned(16))) float  x_s[TLEN];
    __shared__ __attribute__((aligned(16))) float  out_s[TLEN];
    __shared__ __attribute__((aligned(16))) float  h1s[HID];
    __shared__ __attribute__((aligned(16))) float  h2s[HID];
    __shared__ __attribute__((aligned(16))) float4 g1s[HID];     // per-unit gate vec (i,f,g,o)
    __shared__ __attribute__((aligned(16))) float4 g2s[HID];
    __shared__ __attribute__((aligned(16))) float4 biasb[HID];   // L1 bias per gate
    __shared__ __attribute__((aligned(16))) float4 wxb[HID];     // L1 x-weights per gate
    __shared__ __attribute__((aligned(16))) float4 biasd[HID];   // L2 bias per gate
    __shared__ __attribute__((aligned(16))) float  wls[HID];     // head weights
    // L2 gate-o weights, PLANE layout [k][tid]: per-wave contiguous 1024B
    // -> canonical conflict-free ds_read_b128 (R12's 196B stride broke
    // 16B alignment -> b32 splits -> +5300 cy/step stall). 73,728 B.
    __shared__ __attribute__((aligned(16))) float4 wlds[6][NTHR];
    // total LDS ~90.8 KB -> 1 block/CU (occupancy-capped 3 waves/EU)

    const int tid = threadIdx.x;
    const int b   = blockIdx.x;
    const int u   = tid >> 3;   // unit 0..95
    const int kq  = tid & 7;    // K-slice 0..7

    for (int i = tid; i < TLEN; i += NTHR) {
        x_s[i]   = x[b * TLEN + i];
        out_s[i] = 0.0f;
    }

    // ---- Layer-1 weights (regs): gate g row = 96g+u, f4-cols [3kq,3kq+3) ----
    const float4* W0 = reinterpret_cast<const float4*>(Whh0);
    const float4* p;
    p = W0 + (      u) * 24 + 3 * kq;  float4 a00 = p[0], a01 = p[1], a02 = p[2];
    p = W0 + ( 96 + u) * 24 + 3 * kq;  float4 a10 = p[0], a11 = p[1], a12 = p[2];
    p = W0 + (192 + u) * 24 + 3 * kq;  float4 a20 = p[0], a21 = p[1], a22 = p[2];
    p = W0 + (288 + u) * 24 + 3 * kq;  float4 a30 = p[0], a31 = p[1], a32 = p[2];

    // ---- Layer-2: K=192=[Wih1|Whh1]; kq<4 -> Wih1 cols 24kq.., else Whh1.
    //      Gates i,f,g in regs (72 floats); gate o -> LDS planes.
    const float4* W1 = reinterpret_cast<const float4*>(kq < 4 ? Wih1 : Whh1);
    const int c6 = 6 * (kq & 3);
    p = W1 + (      u) * 24 + c6;  float4 bi0=p[0],bi1=p[1],bi2=p[2],bi3=p[3],bi4=p[4],bi5=p[5];
    p = W1 + ( 96 + u) * 24 + c6;  float4 bf0=p[0],bf1=p[1],bf2=p[2],bf3=p[3],bf4=p[4],bf5=p[5];
    p = W1 + (192 + u) * 24 + c6;  float4 bg0=p[0],bg1=p[1],bg2=p[2],bg3=p[3],bg4=p[4],bg5=p[5];
    p = W1 + (288 + u) * 24 + c6;
    wlds[0][tid] = p[0]; wlds[1][tid] = p[1]; wlds[2][tid] = p[2];
    wlds[3][tid] = p[3]; wlds[4][tid] = p[4]; wlds[5][tid] = p[5];

    // ---- pointwise-phase tables (read only by tid<96 threads, from LDS) ----
    if (tid < HID) {
        biasb[tid] = make_float4(bih0[tid]       + bhh0[tid],
                                 bih0[ 96 + tid] + bhh0[ 96 + tid],
                                 bih0[192 + tid] + bhh0[192 + tid],
                                 bih0[288 + tid] + bhh0[288 + tid]);
        wxb[tid]   = make_float4(Wih0[tid], Wih0[96 + tid], Wih0[192 + tid], Wih0[288 + tid]);
        biasd[tid] = make_float4(bih1[tid]       + bhh1[tid],
                                 bih1[ 96 + tid] + bhh1[ 96 + tid],
                                 bih1[192 + tid] + bhh1[192 + tid],
                                 bih1[288 + tid] + bhh1[288 + tid]);
        wls[tid]   = Wl[tid];
        h1s[tid] = 0.0f;  h2s[tid] = 0.0f;
    }

    float c1 = 0.0f, c2 = 0.0f;   // cell state, live in tid<96 threads
    __syncthreads();

    #pragma unroll 1
    for (int t = 0; t < TLEN; ++t) {
        // opaque zero, regenerated per iteration: all LDS pointers built from it
        // are loop-variant -> LICM cannot hoist invariant LDS data into regs
        int zr;
        asm volatile("v_mov_b32 %0, 0" : "=v"(zr));

        // ---- A: layer-1 dots (4 gates x 12 cols), reduce to lane kq==0 ----
        {
            const float4* hA = reinterpret_cast<const float4*>(h1s) + 3 * kq + zr;
            float4 q0 = {0,0,0,0}, q1 = {0,0,0,0}, q2 = {0,0,0,0}, q3 = {0,0,0,0};
            float4 h4;
            h4 = hA[0]; DOT4(q0,a00,h4) DOT4(q1,a10,h4) DOT4(q2,a20,h4) DOT4(q3,a30,h4)
            h4 = hA[1]; DOT4(q0,a01,h4) DOT4(q1,a11,h4) DOT4(q2,a21,h4) DOT4(q3,a31,h4)
            h4 = hA[2]; DOT4(q0,a02,h4) DOT4(q1,a12,h4) DOT4(q2,a22,h4) DOT4(q3,a32,h4)
            float s0 = (q0.x + q0.y) + (q0.z + q0.w);
            float s1 = (q1.x + q1.y) + (q1.z + q1.w);
            float s2 = (q2.x + q2.y) + (q2.z + q2.w);
            float s3 = (q3.x + q3.y) + (q3.z + q3.w);
            RED8(s0) RED8(s1) RED8(s2) RED8(s3)
            if (kq == 0) g1s[u] = make_float4(s0, s1, s2, s3);
        }
        __syncthreads();
        // ---- B: layer-1 pointwise, 96 dedicated threads (1.5 waves) ----
        if (tid < HID) {
            float4 g  = *(g1s + tid + zr);
            float4 bb = *(biasb + tid + zr);
            float4 wx = *(wxb + tid + zr);
            const float xt = x_s[t];
            float gi = sigf(fmaf(wx.x, xt, g.x + bb.x));
            float gf = sigf(fmaf(wx.y, xt, g.y + bb.y));
            float gg = tanh_fast(fmaf(wx.z, xt, g.z + bb.z));
            float go = sigf(fmaf(wx.w, xt, g.w + bb.w));
            c1 = gf * c1 + gi * gg;
            h1s[tid] = go * tanh_fast(c1);
        }
        __syncthreads();
        // ---- C: layer-2 dots (4 gates x 24 cols); kq<4 over h1_t, kq>=4 over h2_{t-1} ----
        {
            const float4* hC = (kq < 4)
                ? reinterpret_cast<const float4*>(h1s) + 6 * kq + zr
                : reinterpret_cast<const float4*>(h2s) + 6 * (kq - 4) + zr;
            const float4* wl = &wlds[0][0] + tid + zr;   // wl[k*NTHR] = wlds[k][tid]
            float4 q0 = {0,0,0,0}, q1 = {0,0,0,0}, q2 = {0,0,0,0}, q3 = {0,0,0,0};
            float4 h4;
            h4 = hC[0]; DOT4(q0,bi0,h4) DOT4(q1,bf0,h4) DOT4(q2,bg0,h4) DOT4(q3,wl[0*NTHR],h4)
            h4 = hC[1]; DOT4(q0,bi1,h4) DOT4(q1,bf1,h4) DOT4(q2,bg1,h4) DOT4(q3,wl[1*NTHR],h4)
            h4 = hC[2]; DOT4(q0,bi2,h4) DOT4(q1,bf2,h4) DOT4(q2,bg2,h4) DOT4(q3,wl[2*NTHR],h4)
            h4 = hC[3]; DOT4(q0,bi3,h4) DOT4(q1,bf3,h4) DOT4(q2,bg3,h4) DOT4(q3,wl[3*NTHR],h4)
            h4 = hC[4]; DOT4(q0,bi4,h4) DOT4(q1,bf4,h4) DOT4(q2,bg4,h4) DOT4(q3,wl[4*NTHR],h4)
            h4 = hC[5]; DOT4(q0,bi5,h4) DOT4(q1,bf5,h4) DOT4(q2,bg5,h4) DOT4(q3,wl[5*NTHR],h4)
            float s0 = (q0.x + q0.y) + (q0.z + q0.w);
            float s1 = (q1.x + q1.y) + (q1.z + q1.w);
            float s2 = (q2.x + q2.y) + (q2.z + q2.w);
            float s3 = (q3.x + q3.y) + (q3.z + q3.w);
            RED8(s0) RED8(s1) RED8(s2) RED8(s3)
            if (kq == 0) g2s[u] = make_float4(s0, s1, s2, s3);
        }
        __syncthreads();
        // ---- D: layer-2 pointwise (96 threads) + head partial; 2-wave reduce ----
        {
            float po = 0.0f;
            if (tid < HID) {
                float4 g  = *(g2s + tid + zr);
                float4 bd = *(biasd + tid + zr);
                float gi = sigf(g.x + bd.x);
                float gf = sigf(g.y + bd.y);
                float gg = tanh_fast(g.z + bd.z);
                float go = sigf(g.w + bd.w);
                c2 = gf * c2 + gi * gg;
                float h2v = go * tanh_fast(c2);
                h2s[tid] = h2v;
                po = *(wls + tid + zr) * h2v;
            }
            if (tid < 128) {   // waves 0,1 fully active -> shfl well-defined
                po += __shfl_xor(po, 1);
                po += __shfl_xor(po, 2);
                po += __shfl_xor(po, 4);
                po += __shfl_xor(po, 8);
                po += __shfl_xor(po, 16);
                po += __shfl_xor(po, 32);
                if ((tid & 63) == 0) atomicAdd(&out_s[t], po);
            }
        }
        // no trailing barrier: D writes h2s (next read in C(t+1), which is
        // behind bar-after-A(t+1): passing that barrier requires ALL threads
        // to have finished D(t)); g1s/g2s/h1s accesses are likewise separated
        // by at least one collective barrier (audited per-buffer).
    }
    __syncthreads();
    const float bl0 = bl[0];
    for (int i = tid; i < TLEN; i += NTHR) out[b * TLEN + i] = out_s[i] + bl0;
}

extern "C" void kernel_launch(void* const* d_in, const int* in_sizes, int n_in,
                              void* d_out, int out_size, void* d_ws, size_t ws_size,
                              hipStream_t stream)
{
    (void)in_sizes; (void)n_in; (void)d_ws; (void)ws_size; (void)out_size;
    const float* x    = (const float*)d_in[0];
    const float* Wih0 = (const float*)d_in[1];
    const float* Whh0 = (const float*)d_in[2];
    const float* bih0 = (const float*)d_in[3];
    const float* bhh0 = (const float*)d_in[4];
    const float* Wih1 = (const float*)d_in[5];
    const float* Whh1 = (const float*)d_in[6];
    const float* bih1 = (const float*)d_in[7];
    const float* bhh1 = (const float*)d_in[8];
    const float* Wl   = (const float*)d_in[9];
    const float* bl   = (const float*)d_in[10];

    lstm2_fused<<<dim3(256), dim3(NTHR), 0, stream>>>(
        x, Wih0, Whh0, bih0, bhh0, Wih1, Whh1, bih1, bhh1, Wl, bl,
        (float*)d_out);
}

// Round 14
// 2551.110 us; speedup vs baseline: 2.1365x; 1.0180x over previous
//
#include <hip/hip_runtime.h>

#define TLEN 1024
#define HID  96
#define NTHR 768

__device__ __forceinline__ float sigf(float x) { return 1.0f / (1.0f + __expf(-x)); }
__device__ __forceinline__ float tanh_fast(float x) {
    float e = __expf(2.0f * x);
    return 1.0f - 2.0f / (e + 1.0f);
}

template <int CTRL>
__device__ __forceinline__ float dpp_add(float s) {
    int t = __builtin_amdgcn_update_dpp(0, __float_as_int(s), CTRL, 0xF, 0xF, true);
    return s + __int_as_float(t);
}
#define DPP_XOR1   0xB1   // quad_perm [1,0,3,2]
#define DPP_XOR2   0x4E   // quad_perm [2,3,0,1]
#define DPP_HMIRR  0x141  // row_half_mirror

// After XOR1+XOR2 each quad holds its quad-sum; HMIRR adds the complementary
// quad -> ALL 8 lanes end with the full 8-slice sum (mirror is symmetric).
#define RED8(S)  S = dpp_add<DPP_XOR1>(S); S = dpp_add<DPP_XOR2>(S); S = dpp_add<DPP_HMIRR>(S);

#define DOT4(A, W, H)                         \
    (A).x = fmaf((W).x, (H).x, (A).x);        \
    (A).y = fmaf((W).y, (H).y, (A).y);        \
    (A).z = fmaf((W).z, (H).z, (A).z);        \
    (A).w = fmaf((W).w, (H).w, (A).w);

extern "C" __global__ void __launch_bounds__(NTHR)
__attribute__((amdgpu_waves_per_eu(3, 3)))
lstm2_fused(const float* __restrict__ x,
            const float* __restrict__ Wih0, const float* __restrict__ Whh0,
            const float* __restrict__ bih0, const float* __restrict__ bhh0,
            const float* __restrict__ Wih1, const float* __restrict__ Whh1,
            const float* __restrict__ bih1, const float* __restrict__ bhh1,
            const float* __restrict__ Wl,   const float* __restrict__ bl,
            float* __restrict__ out)
{
    __shared__ __attribute__((aligned(16))) float  x_s[TLEN];
    __shared__ __attribute__((aligned(16))) float  out_s[TLEN];
    __shared__ __attribute__((aligned(16))) float  h1b[2 * HID];  // double-buffered
    __shared__ __attribute__((aligned(16))) float  h2b[2 * HID];
    __shared__ __attribute__((aligned(16))) float4 biasb[HID];    // L1 bias per gate
    __shared__ __attribute__((aligned(16))) float4 wxb[HID];      // L1 x-weights
    __shared__ __attribute__((aligned(16))) float4 biasd[HID];    // L2 bias per gate
    __shared__ __attribute__((aligned(16))) float  wls[HID];      // head weights
    // L2 gate-o weights, plane layout [k][tid] (R13-proven conflict-free b128)
    __shared__ __attribute__((aligned(16))) float4 wlds[6][NTHR]; // 73,728 B
    // total ~88.5 KB -> 1 block/CU (3 waves/EU budget, R13-proven no-spill)

    const int tid = threadIdx.x;
    const int b   = blockIdx.x;
    const int u   = tid >> 3;   // unit 0..95
    const int kq  = tid & 7;    // K-slice 0..7

    for (int i = tid; i < TLEN; i += NTHR) {
        x_s[i]   = x[b * TLEN + i];
        out_s[i] = 0.0f;
    }

    // ---- Layer-1 weights (regs): gate g row = 96g+u, f4-cols [3kq,3kq+3) ----
    const float4* W0 = reinterpret_cast<const float4*>(Whh0);
    const float4* p;
    p = W0 + (      u) * 24 + 3 * kq;  float4 a00 = p[0], a01 = p[1], a02 = p[2];
    p = W0 + ( 96 + u) * 24 + 3 * kq;  float4 a10 = p[0], a11 = p[1], a12 = p[2];
    p = W0 + (192 + u) * 24 + 3 * kq;  float4 a20 = p[0], a21 = p[1], a22 = p[2];
    p = W0 + (288 + u) * 24 + 3 * kq;  float4 a30 = p[0], a31 = p[1], a32 = p[2];

    // ---- Layer-2: K=192=[Wih1|Whh1]; kq<4 -> Wih1 cols 24(kq&3).., else Whh1.
    //      Gates i,f,g in regs (72 floats); gate o -> LDS planes.
    const float4* W1 = reinterpret_cast<const float4*>(kq < 4 ? Wih1 : Whh1);
    const int c6 = 6 * (kq & 3);
    p = W1 + (      u) * 24 + c6;  float4 bi0=p[0],bi1=p[1],bi2=p[2],bi3=p[3],bi4=p[4],bi5=p[5];
    p = W1 + ( 96 + u) * 24 + c6;  float4 bf0=p[0],bf1=p[1],bf2=p[2],bf3=p[3],bf4=p[4],bf5=p[5];
    p = W1 + (192 + u) * 24 + c6;  float4 bg0=p[0],bg1=p[1],bg2=p[2],bg3=p[3],bg4=p[4],bg5=p[5];
    p = W1 + (288 + u) * 24 + c6;
    wlds[0][tid] = p[0]; wlds[1][tid] = p[1]; wlds[2][tid] = p[2];
    wlds[3][tid] = p[3]; wlds[4][tid] = p[4]; wlds[5][tid] = p[5];

    if (tid < HID) {
        biasb[tid] = make_float4(bih0[tid]       + bhh0[tid],
                                 bih0[ 96 + tid] + bhh0[ 96 + tid],
                                 bih0[192 + tid] + bhh0[192 + tid],
                                 bih0[288 + tid] + bhh0[288 + tid]);
        wxb[tid]   = make_float4(Wih0[tid], Wih0[96 + tid], Wih0[192 + tid], Wih0[288 + tid]);
        biasd[tid] = make_float4(bih1[tid]       + bhh1[tid],
                                 bih1[ 96 + tid] + bhh1[ 96 + tid],
                                 bih1[192 + tid] + bhh1[192 + tid],
                                 bih1[288 + tid] + bhh1[288 + tid]);
        wls[tid]   = Wl[tid];
    }
    if (tid < 2 * HID) { h1b[tid] = 0.0f; h2b[tid] = 0.0f; }

    float c1 = 0.0f, c2 = 0.0f;   // cell state, replicated across the 8 lanes/unit
    __syncthreads();

    #pragma unroll 1
    for (int t = 0; t < TLEN; ++t) {
        const int rd = t & 1, wb = rd ^ 1;
        // opaque zero per iteration: LDS pointers become loop-variant -> LICM
        // cannot hoist invariant LDS data (weights/biases) back into registers
        int zr;
        asm volatile("v_mov_b32 %0, 0" : "=v"(zr));

        // ---- A: layer-1 dots + fused pointwise (ALL lanes, redundant per unit) ----
        {
            const float4* hA = reinterpret_cast<const float4*>(h1b + rd * HID) + 3 * kq + zr;
            float4 q0 = {0,0,0,0}, q1 = {0,0,0,0}, q2 = {0,0,0,0}, q3 = {0,0,0,0};
            float4 h4;
            h4 = hA[0]; DOT4(q0,a00,h4) DOT4(q1,a10,h4) DOT4(q2,a20,h4) DOT4(q3,a30,h4)
            h4 = hA[1]; DOT4(q0,a01,h4) DOT4(q1,a11,h4) DOT4(q2,a21,h4) DOT4(q3,a31,h4)
            h4 = hA[2]; DOT4(q0,a02,h4) DOT4(q1,a12,h4) DOT4(q2,a22,h4) DOT4(q3,a32,h4)
            float s0 = (q0.x + q0.y) + (q0.z + q0.w);
            float s1 = (q1.x + q1.y) + (q1.z + q1.w);
            float s2 = (q2.x + q2.y) + (q2.z + q2.w);
            float s3 = (q3.x + q3.y) + (q3.z + q3.w);
            RED8(s0) RED8(s1) RED8(s2) RED8(s3)   // full sums in ALL 8 lanes
            float4 bb = *(biasb + u + zr);
            float4 wx = *(wxb + u + zr);
            const float xt = x_s[t];
            float gi = sigf(fmaf(wx.x, xt, s0 + bb.x));
            float gf = sigf(fmaf(wx.y, xt, s1 + bb.y));
            float gg = tanh_fast(fmaf(wx.z, xt, s2 + bb.z));
            float go = sigf(fmaf(wx.w, xt, s3 + bb.w));
            c1 = gf * c1 + gi * gg;               // identical in all 8 lanes
            float h1v = go * tanh_fast(c1);
            if (kq == 0) h1b[wb * HID + u] = h1v;
        }
        __syncthreads();   // barrier 1: h1_t visible to all
        // ---- C: layer-2 dots + fused pointwise + head partial ----
        {
            const float4* hC = (kq < 4)
                ? reinterpret_cast<const float4*>(h1b + wb * HID) + 6 * kq + zr
                : reinterpret_cast<const float4*>(h2b + rd * HID) + 6 * (kq - 4) + zr;
            const float4* wl = &wlds[0][0] + tid + zr;   // wl[k*NTHR] = wlds[k][tid]
            float4 q0 = {0,0,0,0}, q1 = {0,0,0,0}, q2 = {0,0,0,0}, q3 = {0,0,0,0};
            float4 h4;
            h4 = hC[0]; DOT4(q0,bi0,h4) DOT4(q1,bf0,h4) DOT4(q2,bg0,h4) DOT4(q3,wl[0*NTHR],h4)
            h4 = hC[1]; DOT4(q0,bi1,h4) DOT4(q1,bf1,h4) DOT4(q2,bg1,h4) DOT4(q3,wl[1*NTHR],h4)
            h4 = hC[2]; DOT4(q0,bi2,h4) DOT4(q1,bf2,h4) DOT4(q2,bg2,h4) DOT4(q3,wl[2*NTHR],h4)
            h4 = hC[3]; DOT4(q0,bi3,h4) DOT4(q1,bf3,h4) DOT4(q2,bg3,h4) DOT4(q3,wl[3*NTHR],h4)
            h4 = hC[4]; DOT4(q0,bi4,h4) DOT4(q1,bf4,h4) DOT4(q2,bg4,h4) DOT4(q3,wl[4*NTHR],h4)
            h4 = hC[5]; DOT4(q0,bi5,h4) DOT4(q1,bf5,h4) DOT4(q2,bg5,h4) DOT4(q3,wl[5*NTHR],h4)
            float s0 = (q0.x + q0.y) + (q0.z + q0.w);
            float s1 = (q1.x + q1.y) + (q1.z + q1.w);
            float s2 = (q2.x + q2.y) + (q2.z + q2.w);
            float s3 = (q3.x + q3.y) + (q3.z + q3.w);
            RED8(s0) RED8(s1) RED8(s2) RED8(s3)
            float4 bd = *(biasd + u + zr);
            float gi = sigf(s0 + bd.x);
            float gf = sigf(s1 + bd.y);
            float gg = tanh_fast(s2 + bd.z);
            float go = sigf(s3 + bd.w);
            c2 = gf * c2 + gi * gg;
            float h2v = go * tanh_fast(c2);
            if (kq == 0) h2b[wb * HID + u] = h2v;
            float po = (kq == 0) ? *(wls + u + zr) * h2v : 0.0f;
            po += __shfl_xor(po, 1);
            po += __shfl_xor(po, 2);
            po += __shfl_xor(po, 4);
            po += __shfl_xor(po, 8);
            po += __shfl_xor(po, 16);
            po += __shfl_xor(po, 32);
            if ((tid & 63) == 0) atomicAdd(&out_s[t], po);
        }
        __syncthreads();   // barrier 2: h2_t visible before next step's C reads
        // race audit: A(t+1) writes h1b[rd(t)] -- last read in A(t), 2 barriers
        // back; C(t+1) writes h2b[rd(t)] -- last read in C(t), 1 barrier back;
        // A(t+1) reads h1b[wb(t)] -- written in A(t), barrier-1 separates.
    }
    __syncthreads();
    const float bl0 = bl[0];
    for (int i = tid; i < TLEN; i += NTHR) out[b * TLEN + i] = out_s[i] + bl0;
}

extern "C" void kernel_launch(void* const* d_in, const int* in_sizes, int n_in,
                              void* d_out, int out_size, void* d_ws, size_t ws_size,
                              hipStream_t stream)
{
    (void)in_sizes; (void)n_in; (void)d_ws; (void)ws_size; (void)out_size;
    const float* x    = (const float*)d_in[0];
    const float* Wih0 = (const float*)d_in[1];
    const float* Whh0 = (const float*)d_in[2];
    const float* bih0 = (const float*)d_in[3];
    const float* bhh0 = (const float*)d_in[4];
    const float* Wih1 = (const float*)d_in[5];
    const float* Whh1 = (const float*)d_in[6];
    const float* bih1 = (const float*)d_in[7];
    const float* bhh1 = (const float*)d_in[8];
    const float* Wl   = (const float*)d_in[9];
    const float* bl   = (const float*)d_in[10];

    lstm2_fused<<<dim3(256), dim3(NTHR), 0, stream>>>(
        x, Wih0, Whh0, bih0, bhh0, Wih1, Whh1, bih1, bhh1, Wl, bl,
        (float*)d_out);
}

// Round 15
// 2304.419 us; speedup vs baseline: 2.3652x; 1.1071x over previous
//
#include <hip/hip_runtime.h>

#define TLEN 1024
#define HID  96
#define NTHR 768

typedef float __attribute__((ext_vector_type(2))) f32x2;

__device__ __forceinline__ float sigf(float x) { return 1.0f / (1.0f + __expf(-x)); }
__device__ __forceinline__ float tanh_fast(float x) {
    float e = __expf(2.0f * x);
    return 1.0f - 2.0f / (e + 1.0f);
}

template <int CTRL>
__device__ __forceinline__ float dpp_add(float s) {
    int t = __builtin_amdgcn_update_dpp(0, __float_as_int(s), CTRL, 0xF, 0xF, true);
    return s + __int_as_float(t);
}
#define DPP_XOR1   0xB1   // quad_perm [1,0,3,2]
#define DPP_XOR2   0x4E   // quad_perm [2,3,0,1]
#define DPP_HMIRR  0x141  // row_half_mirror
// full 8-slice sum lands in ALL 8 lanes (R14-verified)
#define RED8(S)  S = dpp_add<DPP_XOR1>(S); S = dpp_add<DPP_XOR2>(S); S = dpp_add<DPP_HMIRR>(S);

// packed 2-wide fp32 FMA: one instruction does 2 lanes-worth of scalar fma.
// acc/w/h are f32x2 (VGPR pairs). D = S0*S1 + S2 elementwise.
#define PKFMA(ACC, W, H) \
    asm("v_pk_fma_f32 %0, %1, %2, %0" : "+v"(ACC) : "v"(W), "v"(H))

__device__ __forceinline__ f32x2 lo2(float4 v) { f32x2 r; r[0] = v.x; r[1] = v.y; return r; }
__device__ __forceinline__ f32x2 hi2(float4 v) { f32x2 r; r[0] = v.z; r[1] = v.w; return r; }

// per-gate dot contribution of one float4 of weights against one float4 of h
#define DOTP(ACC, W, H4L, H4H)  PKFMA(ACC, lo2(W), H4L); PKFMA(ACC, hi2(W), H4H);

extern "C" __global__ void __launch_bounds__(NTHR)
__attribute__((amdgpu_waves_per_eu(3, 3)))
lstm2_fused(const float* __restrict__ x,
            const float* __restrict__ Wih0, const float* __restrict__ Whh0,
            const float* __restrict__ bih0, const float* __restrict__ bhh0,
            const float* __restrict__ Wih1, const float* __restrict__ Whh1,
            const float* __restrict__ bih1, const float* __restrict__ bhh1,
            const float* __restrict__ Wl,   const float* __restrict__ bl,
            float* __restrict__ out)
{
    __shared__ __attribute__((aligned(16))) float  x_s[TLEN];
    __shared__ __attribute__((aligned(16))) float  out_s[TLEN];
    __shared__ __attribute__((aligned(16))) float  h1b[2 * HID];  // double-buffered
    __shared__ __attribute__((aligned(16))) float  h2b[2 * HID];
    __shared__ __attribute__((aligned(16))) float4 biasb[HID];
    __shared__ __attribute__((aligned(16))) float4 wxb[HID];
    __shared__ __attribute__((aligned(16))) float4 biasd[HID];
    __shared__ __attribute__((aligned(16))) float  wls[HID];
    __shared__ __attribute__((aligned(16))) float4 wlds[6][NTHR]; // gate-o L2 planes
    // ~88.5 KB -> 1 block/CU, 3 waves/EU (R13/R14-proven no-spill budget)

    const int tid = threadIdx.x;
    const int b   = blockIdx.x;
    const int u   = tid >> 3;
    const int kq  = tid & 7;

    for (int i = tid; i < TLEN; i += NTHR) {
        x_s[i]   = x[b * TLEN + i];
        out_s[i] = 0.0f;
    }

    // ---- Layer-1 weights (regs) ----
    const float4* W0 = reinterpret_cast<const float4*>(Whh0);
    const float4* p;
    p = W0 + (      u) * 24 + 3 * kq;  float4 a00 = p[0], a01 = p[1], a02 = p[2];
    p = W0 + ( 96 + u) * 24 + 3 * kq;  float4 a10 = p[0], a11 = p[1], a12 = p[2];
    p = W0 + (192 + u) * 24 + 3 * kq;  float4 a20 = p[0], a21 = p[1], a22 = p[2];
    p = W0 + (288 + u) * 24 + 3 * kq;  float4 a30 = p[0], a31 = p[1], a32 = p[2];

    // ---- Layer-2: gates i,f,g regs; gate o -> LDS planes ----
    const float4* W1 = reinterpret_cast<const float4*>(kq < 4 ? Wih1 : Whh1);
    const int c6 = 6 * (kq & 3);
    p = W1 + (      u) * 24 + c6;  float4 bi0=p[0],bi1=p[1],bi2=p[2],bi3=p[3],bi4=p[4],bi5=p[5];
    p = W1 + ( 96 + u) * 24 + c6;  float4 bf0=p[0],bf1=p[1],bf2=p[2],bf3=p[3],bf4=p[4],bf5=p[5];
    p = W1 + (192 + u) * 24 + c6;  float4 bg0=p[0],bg1=p[1],bg2=p[2],bg3=p[3],bg4=p[4],bg5=p[5];
    p = W1 + (288 + u) * 24 + c6;
    wlds[0][tid] = p[0]; wlds[1][tid] = p[1]; wlds[2][tid] = p[2];
    wlds[3][tid] = p[3]; wlds[4][tid] = p[4]; wlds[5][tid] = p[5];

    if (tid < HID) {
        biasb[tid] = make_float4(bih0[tid]       + bhh0[tid],
                                 bih0[ 96 + tid] + bhh0[ 96 + tid],
                                 bih0[192 + tid] + bhh0[192 + tid],
                                 bih0[288 + tid] + bhh0[288 + tid]);
        wxb[tid]   = make_float4(Wih0[tid], Wih0[96 + tid], Wih0[192 + tid], Wih0[288 + tid]);
        biasd[tid] = make_float4(bih1[tid]       + bhh1[tid],
                                 bih1[ 96 + tid] + bhh1[ 96 + tid],
                                 bih1[192 + tid] + bhh1[192 + tid],
                                 bih1[288 + tid] + bhh1[288 + tid]);
        wls[tid]   = Wl[tid];
    }
    if (tid < 2 * HID) { h1b[tid] = 0.0f; h2b[tid] = 0.0f; }

    float c1 = 0.0f, c2 = 0.0f;   // replicated across the 8 lanes of each unit
    __syncthreads();

    #pragma unroll 1
    for (int t = 0; t < TLEN; ++t) {
        const int rd = t & 1, wb = rd ^ 1;
        int zr;
        asm volatile("v_mov_b32 %0, 0" : "=v"(zr));  // defeats LICM on LDS data

        // ---- A: L1 dots (pk_fma) + fused pointwise (all lanes, redundant/unit) ----
        {
            const float4* hA = reinterpret_cast<const float4*>(h1b + rd * HID) + 3 * kq + zr;
            f32x2 q0 = {0,0}, q1 = {0,0}, q2 = {0,0}, q3 = {0,0};
            float4 h4; f32x2 hl, hh;
            h4 = hA[0]; hl = lo2(h4); hh = hi2(h4);
            DOTP(q0,a00,hl,hh) DOTP(q1,a10,hl,hh) DOTP(q2,a20,hl,hh) DOTP(q3,a30,hl,hh)
            h4 = hA[1]; hl = lo2(h4); hh = hi2(h4);
            DOTP(q0,a01,hl,hh) DOTP(q1,a11,hl,hh) DOTP(q2,a21,hl,hh) DOTP(q3,a31,hl,hh)
            h4 = hA[2]; hl = lo2(h4); hh = hi2(h4);
            DOTP(q0,a02,hl,hh) DOTP(q1,a12,hl,hh) DOTP(q2,a22,hl,hh) DOTP(q3,a32,hl,hh)
            float s0 = q0[0] + q0[1];
            float s1 = q1[0] + q1[1];
            float s2 = q2[0] + q2[1];
            float s3 = q3[0] + q3[1];
            RED8(s0) RED8(s1) RED8(s2) RED8(s3)
            float4 bb = *(biasb + u + zr);
            float4 wx = *(wxb + u + zr);
            const float xt = x_s[t];
            float gi = sigf(fmaf(wx.x, xt, s0 + bb.x));
            float gf = sigf(fmaf(wx.y, xt, s1 + bb.y));
            float gg = tanh_fast(fmaf(wx.z, xt, s2 + bb.z));
            float go = sigf(fmaf(wx.w, xt, s3 + bb.w));
            c1 = gf * c1 + gi * gg;
            float h1v = go * tanh_fast(c1);
            if (kq == 0) h1b[wb * HID + u] = h1v;
        }
        __syncthreads();   // the ONLY barrier per step (race audit below)
        // ---- C: L2 dots (pk_fma) + fused pointwise + head atomic ----
        {
            const float4* hC = (kq < 4)
                ? reinterpret_cast<const float4*>(h1b + wb * HID) + 6 * kq + zr
                : reinterpret_cast<const float4*>(h2b + rd * HID) + 6 * (kq - 4) + zr;
            const float4* wl = &wlds[0][0] + tid + zr;
            f32x2 q0 = {0,0}, q1 = {0,0}, q2 = {0,0}, q3 = {0,0};
            float4 h4, w4; f32x2 hl, hh;
            h4 = hC[0]; hl = lo2(h4); hh = hi2(h4); w4 = wl[0*NTHR];
            DOTP(q0,bi0,hl,hh) DOTP(q1,bf0,hl,hh) DOTP(q2,bg0,hl,hh) DOTP(q3,w4,hl,hh)
            h4 = hC[1]; hl = lo2(h4); hh = hi2(h4); w4 = wl[1*NTHR];
            DOTP(q0,bi1,hl,hh) DOTP(q1,bf1,hl,hh) DOTP(q2,bg1,hl,hh) DOTP(q3,w4,hl,hh)
            h4 = hC[2]; hl = lo2(h4); hh = hi2(h4); w4 = wl[2*NTHR];
            DOTP(q0,bi2,hl,hh) DOTP(q1,bf2,hl,hh) DOTP(q2,bg2,hl,hh) DOTP(q3,w4,hl,hh)
            h4 = hC[3]; hl = lo2(h4); hh = hi2(h4); w4 = wl[3*NTHR];
            DOTP(q0,bi3,hl,hh) DOTP(q1,bf3,hl,hh) DOTP(q2,bg3,hl,hh) DOTP(q3,w4,hl,hh)
            h4 = hC[4]; hl = lo2(h4); hh = hi2(h4); w4 = wl[4*NTHR];
            DOTP(q0,bi4,hl,hh) DOTP(q1,bf4,hl,hh) DOTP(q2,bg4,hl,hh) DOTP(q3,w4,hl,hh)
            h4 = hC[5]; hl = lo2(h4); hh = hi2(h4); w4 = wl[5*NTHR];
            DOTP(q0,bi5,hl,hh) DOTP(q1,bf5,hl,hh) DOTP(q2,bg5,hl,hh) DOTP(q3,w4,hl,hh)
            float s0 = q0[0] + q0[1];
            float s1 = q1[0] + q1[1];
            float s2 = q2[0] + q2[1];
            float s3 = q3[0] + q3[1];
            RED8(s0) RED8(s1) RED8(s2) RED8(s3)
            float4 bd = *(biasd + u + zr);
            float gi = sigf(s0 + bd.x);
            float gf = sigf(s1 + bd.y);
            float gg = tanh_fast(s2 + bd.z);
            float go = sigf(s3 + bd.w);
            c2 = gf * c2 + gi * gg;
            float h2v = go * tanh_fast(c2);
            if (kq == 0) {
                h2b[wb * HID + u] = h2v;
                // fire-and-forget float atomic (no return -> no waitcnt, off the
                // critical chain); LDS atomic unit serializes the 96 adds.
                atomicAdd(&out_s[t], *(wls + u + zr) * h2v);
            }
        }
        // 1-barrier race audit: A(t+1) writes h1b[rd(t)] -- its only readers ran
        // in A(t), before barrier(t), and every thread entering A(t+1) passed
        // barrier(t). C(t+1) reads h2b[wb(t)] / writes h2b[rd(t)] -- the
        // conflicting accesses in C(t) are separated by barrier(t+1). h1b[wb(t)]
        // is read-only in both C(t) and A(t+1).
    }
    __syncthreads();
    const float bl0 = bl[0];
    for (int i = tid; i < TLEN; i += NTHR) out[b * TLEN + i] = out_s[i] + bl0;
}

extern "C" void kernel_launch(void* const* d_in, const int* in_sizes, int n_in,
                              void* d_out, int out_size, void* d_ws, size_t ws_size,
                              hipStream_t stream)
{
    (void)in_sizes; (void)n_in; (void)d_ws; (void)ws_size; (void)out_size;
    const float* x    = (const float*)d_in[0];
    const float* Wih0 = (const float*)d_in[1];
    const float* Whh0 = (const float*)d_in[2];
    const float* bih0 = (const float*)d_in[3];
    const float* bhh0 = (const float*)d_in[4];
    const float* Wih1 = (const float*)d_in[5];
    const float* Whh1 = (const float*)d_in[6];
    const float* bih1 = (const float*)d_in[7];
    const float* bhh1 = (const float*)d_in[8];
    const float* Wl   = (const float*)d_in[9];
    const float* bl   = (const float*)d_in[10];

    lstm2_fused<<<dim3(256), dim3(NTHR), 0, stream>>>(
        x, Wih0, Whh0, bih0, bhh0, Wih1, Whh1, bih1, bhh1, Wl, bl,
        (float*)d_out);
}